// Round 3
// baseline (1013.651 us; speedup 1.0000x reference)
//
#include <hip/hip_runtime.h>
#include <hip/hip_bf16.h>

// LDS.sampleX: x[t] = A x[t-1] + Q e[t], parallelized via contraction warm-up.
// 20000 chunks x T=50 steps, W=30 warmup. 16 chunks per wave; per step:
// X_new(64x16) = A*X + Q*E via 16x16x32 bf16 MFMA.
//
// Staging: __builtin_amdgcn_global_load_lds (async DMA to LDS, fp32, zero VGPR
// cost), DOUBLE-buffered with DEPTH-1 prefetch. Round-2's depth-2 prefetch
// raced: DMA(b+2) targets buffer (b+2)&1 == b&1, overwriting the batch being
// read. Fix: issue DMA(b+2) AFTER the steps that consume buffer b&1, with a
// sched_barrier so the compiler can't hoist the DMA above the ds_reads.
//
// vmcnt accounting (in-order retire): each dma_stage = exactly 16 vmem ops
// (block0/chunk0 warm-up head uses one clamped VGPR load, preserving count).
// To prove DMA(b) retired at iter b, wait vmcnt(16 + #stores issued in iter
// b-1): 16 for b<=7, 24 at b=8, 32 for b=9..18, 16 for the last batch. Never 0
// in steady state -> prefetch and output stores stay in flight.

using bf16x8 = __attribute__((ext_vector_type(8))) short;
using s16x4  = __attribute__((ext_vector_type(4))) short;
using f32x4  = __attribute__((ext_vector_type(4))) float;

#define N_STEPS   1000000
#define XD        64
#define T_CHUNK   50
#define WARM      30
#define STOT      (WARM + T_CHUNK)      /* 80 = NB*BATCH */
#define BATCH     4
#define NB        (STOT / BATCH)        /* 20 */
#define N_CHUNKS  (N_STEPS / T_CHUNK)   /* 20000 */
#define N_BLOCKS  (N_CHUNKS / 16)       /* 1250 */
#define CPAD      (BATCH * XD + 4)      /* 260 f32 per chunk region (16B pad) */
#define PAD       72                    /* state LDS row stride (bf16 elems) */

typedef const __attribute__((address_space(1))) void* as1cv;
typedef __attribute__((address_space(3))) void*       as3v;

__device__ __forceinline__ short f2bf_rne(float f) {
    unsigned u = __builtin_bit_cast(unsigned, f);
    u += 0x7FFFu + ((u >> 16) & 1u);
    return (short)(u >> 16);
}
__device__ __forceinline__ float bf2f(short s) {
    return __builtin_bit_cast(float, ((unsigned)(unsigned short)s) << 16);
}
__device__ __forceinline__ short f2bf_hw(float f) {   // HW RNE convert
    return __builtin_bit_cast(short, __float2bfloat16(f));
}

__global__ __launch_bounds__(64, 1) void lds_scan_kernel(
    const float* __restrict__ eps,   // [N_STEPS, 64]
    const float* __restrict__ A,     // [64, 64] row-major
    const float* __restrict__ Q,     // [64, 64]
    const float* __restrict__ Q0,    // [64, 64]
    const float* __restrict__ x0,    // [64]
    float* __restrict__ out)         // [N_STEPS, 64]
{
    __shared__ float Eb32[2 * 16 * CPAD];  // staged eps fp32, double-buffered (~33 KB)
    __shared__ short Xh[16 * PAD];         // state hi, [chunk][dim] bf16
    __shared__ short Xl[16 * PAD];         // state lo (residual)
    __shared__ float corr[XD];             // chunk-0 t=0 correction: x0 + (Q0-Q) e0
    __shared__ float e0s[XD];

    const int lane = threadIdx.x;    // 0..63 (one wave per block)
    const int cl   = lane & 15;      // chunk column (n in MFMA B and C/D layouts)
    const int g    = lane >> 4;      // quad index

    // zero initial state
    for (int i = lane; i < 16 * PAD; i += 64) { Xh[i] = 0; Xl[i] = 0; }

    if (blockIdx.x == 0) e0s[lane] = eps[lane];
    __syncthreads();
    if (blockIdx.x == 0) {
        float c = x0[lane];
        #pragma unroll 8
        for (int j = 0; j < XD; ++j)
            c += (Q0[lane * XD + j] - Q[lane * XD + j]) * e0s[j];
        corr[lane] = c;
    }
    __syncthreads();

    // Constant A/Q fragments, MFMA A-operand layout:
    // lane holds M[mt*16 + (lane&15)][ks*32 + (lane>>4)*8 + j], j=0..7
    bf16x8 Af[4][2], Qf[4][2];
    #pragma unroll
    for (int mt = 0; mt < 4; ++mt) {
        #pragma unroll
        for (int ks = 0; ks < 2; ++ks) {
            const float* ap = A + (mt * 16 + cl) * XD + ks * 32 + g * 8;
            const float* qp = Q + (mt * 16 + cl) * XD + ks * 32 + g * 8;
            bf16x8 af, qf;
            #pragma unroll
            for (int j = 0; j < 8; ++j) { af[j] = f2bf_rne(ap[j]); qf[j] = f2bf_rne(qp[j]); }
            Af[mt][ks] = af; Qf[mt][ks] = qf;
        }
    }

    const long chunk = (long)blockIdx.x * 16 + cl;       // this lane's chunk column
    float* po = out + chunk * ((long)T_CHUNK * XD);      // output base for this chunk

    // --- async DMA staging: batch b -> Eb32[b&1]. Exactly 16 vmem ops. -----
    auto dma_stage = [&](int b) {
        float* lbase = &Eb32[(b & 1) * (16 * CPAD)];
        #pragma unroll
        for (int c = 0; c < 16; ++c) {
            const long tb = ((long)blockIdx.x * 16 + c) * T_CHUNK - WARM + (long)b * BATCH;
            float* lp = lbase + c * CPAD;
            if (tb >= 0) {
                // one call = 64 lanes x 16B = 4 eps rows; LDS dst linear lane*16
                const float* gp = eps + (tb + g) * XD + cl * 4;
                __builtin_amdgcn_global_load_lds((as1cv)gp, (as3v)lp, 16, 0, 0);
            } else {
                // block 0, chunk 0 warm-up head: clamped VGPR load (still 1 vmem op)
                const long trow = tb + g;
                const long row  = trow < 0 ? 0 : trow;
                f32x4 v = *(const f32x4*)(eps + row * XD + cl * 4);
                if (trow < 0) v = (f32x4){0.f, 0.f, 0.f, 0.f};
                *(f32x4*)(lp + lane * 4) = v;
            }
        }
    };

    // --- one scan step ------------------------------------------------------
    auto step = [&](const float* ebase, int k, int s) {
        // E fragments: fp32 from LDS, convert to bf16 (RNE). Off the state chain.
        const float* ep = ebase + cl * CPAD + k * XD;
        const f32x4 e0a = *(const f32x4*)(ep + g * 8);
        const f32x4 e0b = *(const f32x4*)(ep + g * 8 + 4);
        const f32x4 e1a = *(const f32x4*)(ep + 32 + g * 8);
        const f32x4 e1b = *(const f32x4*)(ep + 32 + g * 8 + 4);
        bf16x8 ef0, ef1;
        #pragma unroll
        for (int j = 0; j < 4; ++j) {
            ef0[j]     = f2bf_hw(e0a[j]);
            ef0[4 + j] = f2bf_hw(e0b[j]);
            ef1[j]     = f2bf_hw(e1a[j]);
            ef1[4 + j] = f2bf_hw(e1b[j]);
        }

        // state fragments from LDS
        bf16x8 xh0 = *(const bf16x8*)&Xh[cl * PAD +  0 + g * 8];
        bf16x8 xh1 = *(const bf16x8*)&Xh[cl * PAD + 32 + g * 8];
        bf16x8 xl0 = *(const bf16x8*)&Xl[cl * PAD +  0 + g * 8];
        bf16x8 xl1 = *(const bf16x8*)&Xl[cl * PAD + 32 + g * 8];

        // X_new = A*(xh + xl) + Q*e, fp32 accumulate.
        // Q*e first (state-independent); two parallel chains (state-dep depth 2).
        f32x4 acc[4];
        #pragma unroll
        for (int mt = 0; mt < 4; ++mt) {
            f32x4 a  = {0.f, 0.f, 0.f, 0.f};
            f32x4 a2 = {0.f, 0.f, 0.f, 0.f};
            a  = __builtin_amdgcn_mfma_f32_16x16x32_bf16(Qf[mt][0], ef0, a,  0, 0, 0);
            a2 = __builtin_amdgcn_mfma_f32_16x16x32_bf16(Qf[mt][1], ef1, a2, 0, 0, 0);
            a  = __builtin_amdgcn_mfma_f32_16x16x32_bf16(Af[mt][0], xh0, a,  0, 0, 0);
            a2 = __builtin_amdgcn_mfma_f32_16x16x32_bf16(Af[mt][1], xh1, a2, 0, 0, 0);
            a  = __builtin_amdgcn_mfma_f32_16x16x32_bf16(Af[mt][0], xl0, a,  0, 0, 0);
            a2 = __builtin_amdgcn_mfma_f32_16x16x32_bf16(Af[mt][1], xl1, a2, 0, 0, 0);
            acc[mt] = a + a2;
        }

        // chunk 0, t==0: inject x0 + (Q0 - Q) e0 so result = x0 + Q0 e0
        if (blockIdx.x == 0 && s == WARM && cl == 0) {
            #pragma unroll
            for (int mt = 0; mt < 4; ++mt)
                #pragma unroll
                for (int r = 0; r < 4; ++r)
                    acc[mt][r] += corr[mt * 16 + g * 4 + r];
        }

        // write back compensated state (C/D layout: lane=chunk cl, dims mt*16+g*4+r).
        // Truncation split: pair precision equals RNE split; hi is 1 VALU op.
        #pragma unroll
        for (int mt = 0; mt < 4; ++mt) {
            s16x4 hi, lo;
            #pragma unroll
            for (int r = 0; r < 4; ++r) {
                const float v = acc[mt][r];
                const short h = (short)(__builtin_bit_cast(unsigned, v) >> 16);
                hi[r] = h;
                const float rem = v - bf2f(h);
                lo[r] = (short)(__builtin_bit_cast(unsigned, rem) >> 16);
            }
            *(s16x4*)&Xh[cl * PAD + mt * 16 + g * 4] = hi;
            *(s16x4*)&Xl[cl * PAD + mt * 16 + g * 4] = lo;
        }

        // store outputs (fp32, float4 per mt-tile)
        if (s >= WARM) {
            float* op = po + (long)(s - WARM) * XD;
            #pragma unroll
            for (int mt = 0; mt < 4; ++mt)
                *(f32x4*)(op + mt * 16 + g * 4) = acc[mt];
        }
    };

    auto run_batch = [&](int b) {
        const float* ebase = &Eb32[(b & 1) * (16 * CPAD)];
        #pragma unroll
        for (int k = 0; k < BATCH; ++k) step(ebase, k, b * BATCH + k);
    };
    // ------------------------------------------------------------------------

    dma_stage(0);
    dma_stage(1);

    // b = 0..7: no stores issued in iter b-1 -> vmcnt(16) proves DMA(b) done
    for (int b = 0; b < 8; ++b) {
        asm volatile("s_waitcnt vmcnt(16)" ::: "memory");
        run_batch(b);
        __builtin_amdgcn_sched_barrier(0);   // keep DMA below this batch's ds_reads
        dma_stage(b + 2);
    }
    // b = 8: iter 7 issued 8 stores (s=30,31) -> vmcnt(24)
    {
        asm volatile("s_waitcnt vmcnt(24)" ::: "memory");
        run_batch(8);
        __builtin_amdgcn_sched_barrier(0);
        dma_stage(10);
    }
    // b = 9..17: 16 stores + 16 DMA after DMA(b) -> vmcnt(32)
    for (int b = 9; b < 18; ++b) {
        asm volatile("s_waitcnt vmcnt(32)" ::: "memory");
        run_batch(b);
        __builtin_amdgcn_sched_barrier(0);
        dma_stage(b + 2);
    }
    // b = 18: stores_17(16) + DMA(19)(16) follow DMA(18) -> vmcnt(32); no prefetch
    {
        asm volatile("s_waitcnt vmcnt(32)" ::: "memory");
        run_batch(18);
    }
    // b = 19: only stores_18(16) follow DMA(19) -> vmcnt(16)
    {
        asm volatile("s_waitcnt vmcnt(16)" ::: "memory");
        run_batch(19);
    }
}

extern "C" void kernel_launch(void* const* d_in, const int* in_sizes, int n_in,
                              void* d_out, int out_size, void* d_ws, size_t ws_size,
                              hipStream_t stream) {
    const float* eps = (const float*)d_in[0];   // norm_samp [1e6, 64]
    const float* A   = (const float*)d_in[1];   // [64,64]
    const float* Q   = (const float*)d_in[2];   // QChol [64,64]
    const float* Q0  = (const float*)d_in[3];   // Q0Chol [64,64]
    const float* x0  = (const float*)d_in[4];   // [64]
    float* out = (float*)d_out;

    lds_scan_kernel<<<N_BLOCKS, 64, 0, stream>>>(eps, A, Q, Q0, x0, out);
}

// Round 4
// 484.151 us; speedup vs baseline: 2.0937x; 2.0937x over previous
//
#include <hip/hip_runtime.h>
#include <hip/hip_bf16.h>

// LDS.sampleX: x[t] = A x[t-1] + Q e[t], parallelized via contraction warm-up.
// 20000 chunks x T=50 steps, W=30 warmup. 16 chunks per wave; per step:
// X_new(64x16) = A*X + Q*E via 16x16x32 bf16 MFMA.
//
// Round-4 structure: NO staging for E. Each lane loads its MFMA B-fragment
// directly global->VGPR (4 x dwordx4 per step; 16 fully-used 64B lines per
// instruction). 2-step register pipeline: loads for batch b+1 issue before
// batch b's compute, pinned by a compile-time memory fence (prevents the
// round-1 load-sinking; the WAR on the single E buffer prevents hoisting
// past the converts). No vmcnt asm - compiler inserts exact counted waits.
// LDS holds only state (bf16 hi+lo compensated) ~5KB -> high residency.
// Loop split: warm batches (zero-mask for chunk-0 head, no stores) then
// main batches (stores, no mask).

using bf16x8 = __attribute__((ext_vector_type(8))) short;
using s16x4  = __attribute__((ext_vector_type(4))) short;
using f32x4  = __attribute__((ext_vector_type(4))) float;

#define N_STEPS   1000000
#define XD        64
#define T_CHUNK   50
#define WARM      30
#define STOT      (WARM + T_CHUNK)      /* 80 */
#define NBATCH    (STOT / 2)            /* 40 two-step batches */
#define WBATCH    (WARM / 2)            /* 15 warm batches */
#define N_CHUNKS  (N_STEPS / T_CHUNK)   /* 20000 */
#define N_BLOCKS  (N_CHUNKS / 16)       /* 1250 */
#define PAD       66                    /* state LDS row stride (bf16 elems) */

__device__ __forceinline__ short f2bf_rne(float f) {
    unsigned u = __builtin_bit_cast(unsigned, f);
    u += 0x7FFFu + ((u >> 16) & 1u);
    return (short)(u >> 16);
}
__device__ __forceinline__ float bf2f(short s) {
    return __builtin_bit_cast(float, ((unsigned)(unsigned short)s) << 16);
}
__device__ __forceinline__ short f2bf_hw(float f) {   // HW RNE convert
    return __builtin_bit_cast(short, __float2bfloat16(f));
}

__global__ __launch_bounds__(64, 1) void lds_scan_kernel(
    const float* __restrict__ eps,   // [N_STEPS, 64]
    const float* __restrict__ A,     // [64, 64] row-major
    const float* __restrict__ Q,     // [64, 64]
    const float* __restrict__ Q0,    // [64, 64]
    const float* __restrict__ x0,    // [64]
    float* __restrict__ out)         // [N_STEPS, 64]
{
    __shared__ short Xh[16 * PAD];   // state hi, [chunk][dim] bf16
    __shared__ short Xl[16 * PAD];   // state lo (residual)
    __shared__ float corr[XD];       // chunk-0 t=0 correction: x0 + (Q0-Q) e0
    __shared__ float e0s[XD];

    const int lane = threadIdx.x;    // 0..63 (one wave per block)
    const int cl   = lane & 15;      // chunk column (n in MFMA B and C/D layouts)
    const int g    = lane >> 4;      // quad index

    for (int i = lane; i < 16 * PAD; i += 64) { Xh[i] = 0; Xl[i] = 0; }

    if (blockIdx.x == 0) e0s[lane] = eps[lane];
    __syncthreads();
    if (blockIdx.x == 0) {
        float c = x0[lane];
        #pragma unroll 8
        for (int j = 0; j < XD; ++j)
            c += (Q0[lane * XD + j] - Q[lane * XD + j]) * e0s[j];
        corr[lane] = c;
    }
    __syncthreads();

    // Constant A/Q fragments, MFMA A-operand layout:
    // lane holds M[mt*16 + (lane&15)][ks*32 + (lane>>4)*8 + j], j=0..7
    bf16x8 Af[4][2], Qf[4][2];
    #pragma unroll
    for (int mt = 0; mt < 4; ++mt) {
        #pragma unroll
        for (int ks = 0; ks < 2; ++ks) {
            const float* ap = A + (mt * 16 + cl) * XD + ks * 32 + g * 8;
            const float* qp = Q + (mt * 16 + cl) * XD + ks * 32 + g * 8;
            bf16x8 af, qf;
            #pragma unroll
            for (int j = 0; j < 8; ++j) { af[j] = f2bf_rne(ap[j]); qf[j] = f2bf_rne(qp[j]); }
            Af[mt][ks] = af; Qf[mt][ks] = qf;
        }
    }

    const int chunk = blockIdx.x * 16 + cl;          // this lane's chunk column
    const int tb    = chunk * T_CHUNK - WARM;        // lane's step->row offset
    float* po = out + (long)chunk * T_CHUNK * XD;    // output base for this chunk

    // E pipeline: one 2-step batch of B-fragment floats, loaded direct to regs.
    // E[k][0..1] = dims g*8..g*8+7 (ks=0), E[k][2..3] = dims 32+g*8.. (ks=1).
    f32x4 E[2][4];

    auto load_pair = [&](int b) {
        #pragma unroll
        for (int k = 0; k < 2; ++k) {
            const int t  = tb + 2 * b + k;
            const int tc = t < 0 ? 0 : t;            // clamp (chunk-0 head only)
            const float* p = eps + (long)tc * XD + g * 8;
            E[k][0] = *(const f32x4*)(p);
            E[k][1] = *(const f32x4*)(p + 4);
            E[k][2] = *(const f32x4*)(p + 32);
            E[k][3] = *(const f32x4*)(p + 36);
        }
    };

    auto convert = [&](int k, bool maskable, int s, bf16x8& ef0, bf16x8& ef1) {
        const bool z = maskable && ((tb + s) < 0);   // per-lane: chunk-0 warm head
        #pragma unroll
        for (int j = 0; j < 4; ++j) {
            const float v0 = z ? 0.f : E[k][0][j];
            const float v1 = z ? 0.f : E[k][1][j];
            const float v2 = z ? 0.f : E[k][2][j];
            const float v3 = z ? 0.f : E[k][3][j];
            ef0[j]     = f2bf_hw(v0);
            ef0[4 + j] = f2bf_hw(v1);
            ef1[j]     = f2bf_hw(v2);
            ef1[4 + j] = f2bf_hw(v3);
        }
    };

    auto step = [&](bf16x8 ef0, bf16x8 ef1, int s, bool store_out, bool inject) {
        // state fragments from LDS
        bf16x8 xh0 = *(const bf16x8*)&Xh[cl * PAD +  0 + g * 8];
        bf16x8 xh1 = *(const bf16x8*)&Xh[cl * PAD + 32 + g * 8];
        bf16x8 xl0 = *(const bf16x8*)&Xl[cl * PAD +  0 + g * 8];
        bf16x8 xl1 = *(const bf16x8*)&Xl[cl * PAD + 32 + g * 8];

        // X_new = A*(xh + xl) + Q*e; Q*e first (state-independent), two
        // parallel accumulator chains (state-dependent MFMA depth = 2).
        f32x4 acc[4];
        #pragma unroll
        for (int mt = 0; mt < 4; ++mt) {
            f32x4 a  = {0.f, 0.f, 0.f, 0.f};
            f32x4 a2 = {0.f, 0.f, 0.f, 0.f};
            a  = __builtin_amdgcn_mfma_f32_16x16x32_bf16(Qf[mt][0], ef0, a,  0, 0, 0);
            a2 = __builtin_amdgcn_mfma_f32_16x16x32_bf16(Qf[mt][1], ef1, a2, 0, 0, 0);
            a  = __builtin_amdgcn_mfma_f32_16x16x32_bf16(Af[mt][0], xh0, a,  0, 0, 0);
            a2 = __builtin_amdgcn_mfma_f32_16x16x32_bf16(Af[mt][1], xh1, a2, 0, 0, 0);
            a  = __builtin_amdgcn_mfma_f32_16x16x32_bf16(Af[mt][0], xl0, a,  0, 0, 0);
            a2 = __builtin_amdgcn_mfma_f32_16x16x32_bf16(Af[mt][1], xl1, a2, 0, 0, 0);
            acc[mt] = a + a2;
        }

        // chunk 0, t==0: inject x0 + (Q0 - Q) e0 so result = x0 + Q0 e0
        if (inject && blockIdx.x == 0 && cl == 0) {
            #pragma unroll
            for (int mt = 0; mt < 4; ++mt)
                #pragma unroll
                for (int r = 0; r < 4; ++r)
                    acc[mt][r] += corr[mt * 16 + g * 4 + r];
        }

        // write back compensated state (C/D layout: lane=chunk cl, dims mt*16+g*4+r).
        // Truncation split: pair precision equals RNE split; hi is 1 VALU op.
        #pragma unroll
        for (int mt = 0; mt < 4; ++mt) {
            s16x4 hi, lo;
            #pragma unroll
            for (int r = 0; r < 4; ++r) {
                const float v = acc[mt][r];
                const short h = (short)(__builtin_bit_cast(unsigned, v) >> 16);
                hi[r] = h;
                const float rem = v - bf2f(h);
                lo[r] = (short)(__builtin_bit_cast(unsigned, rem) >> 16);
            }
            *(s16x4*)&Xh[cl * PAD + mt * 16 + g * 4] = hi;
            *(s16x4*)&Xl[cl * PAD + mt * 16 + g * 4] = lo;
        }

        if (store_out) {
            float* op = po + (long)(s - WARM) * XD;
            #pragma unroll
            for (int mt = 0; mt < 4; ++mt)
                *(f32x4*)(op + mt * 16 + g * 4) = acc[mt];
        }
    };
    // ------------------------------------------------------------------------

    load_pair(0);
    asm volatile("" ::: "memory");   // pin prologue loads before the loop

    // warm batches: steps 0..29, zero-mask chunk-0 head, no output stores
    for (int b = 0; b < WBATCH; ++b) {
        bf16x8 e00, e01, e10, e11;
        convert(0, true, 2 * b,     e00, e01);
        convert(1, true, 2 * b + 1, e10, e11);
        load_pair(b + 1);            // prefetch next batch into E (after converts)
        asm volatile("" ::: "memory");  // loads stay here; steps' mem ops stay below
        step(e00, e01, 2 * b,     false, false);
        step(e10, e11, 2 * b + 1, false, false);
    }
    // main batches: steps 30..79, stores; corr injected at s==30 (b==WBATCH, k==0)
    for (int b = WBATCH; b < NBATCH; ++b) {
        bf16x8 e00, e01, e10, e11;
        convert(0, false, 2 * b,     e00, e01);
        convert(1, false, 2 * b + 1, e10, e11);
        if (b + 1 < NBATCH) load_pair(b + 1);
        asm volatile("" ::: "memory");
        step(e00, e01, 2 * b,     true, b == WBATCH);
        step(e10, e11, 2 * b + 1, true, false);
    }
}

extern "C" void kernel_launch(void* const* d_in, const int* in_sizes, int n_in,
                              void* d_out, int out_size, void* d_ws, size_t ws_size,
                              hipStream_t stream) {
    const float* eps = (const float*)d_in[0];   // norm_samp [1e6, 64]
    const float* A   = (const float*)d_in[1];   // [64,64]
    const float* Q   = (const float*)d_in[2];   // QChol [64,64]
    const float* Q0  = (const float*)d_in[3];   // Q0Chol [64,64]
    const float* x0  = (const float*)d_in[4];   // [64]
    float* out = (float*)d_out;

    lds_scan_kernel<<<N_BLOCKS, 64, 0, stream>>>(eps, A, Q, Q0, x0, out);
}